// Round 2
// baseline (350.432 us; speedup 1.0000x reference)
//
#include <hip/hip_runtime.h>

// ---------------------------------------------------------------------------
// DCGRU cell on MI355X.
// B=32, N=1024, C_IN=2, H=32, S=2, K=2, NUM_MAT=5, c_cat=34, feats=5*34=170.
//
// Layouts:
//   supports (fp32 input): [B][S][N][N]
//   A_bf16 (ws):           [B][S][N][N] bf16
//   H buffers (ws):        per b: 5 slots x 3 ct x [16 ch][1024 n] bf16 ("XT")
//     slot j channel c of row n -> H[b*245760 + (3*j + c/16)*16384 + (c%16)*1024 + n]
//     channels 34..47 of each slot are zero padding.
//   u_buf (ws):            [B][32][N] fp32
//
// Output: d_out = (outputs, outputs), each B*N*H = 1,048,576 fp32.
// ---------------------------------------------------------------------------

#define NN   1024
#define HB   245760   // 15*16*1024 elems per batch in an H buffer
#define SUBT 16384    // 16*1024
#define OUTCOPY 1048576  // elements per tuple member

typedef float  f32x4  __attribute__((ext_vector_type(4)));
typedef short  s16x4  __attribute__((ext_vector_type(4)));
typedef short  s16x8  __attribute__((ext_vector_type(8)));
typedef __bf16 bf16x8 __attribute__((ext_vector_type(8)));
typedef unsigned int u32x4 __attribute__((ext_vector_type(4)));

__device__ __forceinline__ unsigned short f32_bf16(float f) {
  unsigned int u = __float_as_uint(f);
  u += 0x7FFFu + ((u >> 16) & 1u);        // round-to-nearest-even
  return (unsigned short)(u >> 16);
}
__device__ __forceinline__ float bf16_f32(unsigned short h) {
  return __uint_as_float(((unsigned int)h) << 16);
}

// ---------------------------------------------------------------------------
// supports fp32 -> bf16
// ---------------------------------------------------------------------------
__global__ __launch_bounds__(256)
void cvt_bf16(const float* __restrict__ src, unsigned short* __restrict__ dst, int n4) {
  int i = blockIdx.x * 256 + threadIdx.x;
  int stride = gridDim.x * 256;
  for (; i < n4; i += stride) {
    float4 v = ((const float4*)src)[i];
    s16x4 o;
    o.x = (short)f32_bf16(v.x);
    o.y = (short)f32_bf16(v.y);
    o.z = (short)f32_bf16(v.z);
    o.w = (short)f32_bf16(v.w);
    ((s16x4*)dst)[i] = o;
  }
}

// ---------------------------------------------------------------------------
// pack x1 = [inputs, states] into H1 slot 0 (XT layout, bf16, zero pad)
// one thread per (b, n) row
// ---------------------------------------------------------------------------
__global__ __launch_bounds__(256)
void pack_x1(const float* __restrict__ inputs, const float* __restrict__ states,
             unsigned short* __restrict__ H1) {
  int gid = blockIdx.x * 256 + threadIdx.x;   // 0..32767
  int b = gid >> 10, n = gid & 1023;
  unsigned short* xb = H1 + (size_t)b * HB;   // slot 0
  xb[0 * NN + n] = f32_bf16(inputs[gid * 2 + 0]);
  xb[1 * NN + n] = f32_bf16(inputs[gid * 2 + 1]);
#pragma unroll
  for (int o = 0; o < 32; ++o) {
    int ch = 2 + o;
    xb[(ch >> 4) * SUBT + (ch & 15) * NN + n] = f32_bf16(states[gid * 32 + o]);
  }
#pragma unroll
  for (int ch = 34; ch < 48; ++ch)
    xb[2 * SUBT + (ch & 15) * NN + n] = 0;
}

// ---------------------------------------------------------------------------
// hop kernel: Y = A @ X  (per b, per s), M=N=1024 rows, 48 channels (34 real)
// BM=128 rows/block, BK=64, 4 waves, each wave: 2 m-tiles x 3 n-tiles of
// mfma_f32_16x16x32_bf16. XOR-swizzled LDS (16B granule, row&7).
// ---------------------------------------------------------------------------
template <int ABF16>
__global__ __launch_bounds__(256)
void hop_kernel(const float* __restrict__ Af32,
                const unsigned short* __restrict__ Abf,
                const unsigned short* __restrict__ Hin,
                unsigned short* __restrict__ Hout,
                int si0, int si1, int so0, int so1) {
  __shared__ u32x4 lA4[1024];   // 16 KB: A tile [128 rows][64 k] bf16, swizzled
  __shared__ u32x4 lX4[384];    // 6 KB:  X tiles 3 x [16 ch][64 k] bf16, swizzled

  const int tid  = threadIdx.x;
  const int wave = tid >> 6, lane = tid & 63;
  const int l15  = lane & 15,  l4  = lane >> 4;
  const int mblk = blockIdx.x, b = blockIdx.y, s = blockIdx.z;
  const int slot_in  = s ? si1 : si0;
  const int slot_out = s ? so1 : so0;

  const unsigned short* Xb = Hin  + (size_t)b * HB + (size_t)slot_in  * 3 * SUBT;
  unsigned short*       Yb = Hout + (size_t)b * HB + (size_t)slot_out * 3 * SUBT;
  const size_t arow0 = ((size_t)(b * 2 + s) * NN + (size_t)mblk * 128) * NN;

  f32x4 acc[2][3];
#pragma unroll
  for (int mt = 0; mt < 2; ++mt)
#pragma unroll
    for (int nt = 0; nt < 3; ++nt)
#pragma unroll
      for (int e = 0; e < 4; ++e) acc[mt][nt][e] = 0.f;

  char* lAb = (char*)lA4;
  char* lXb = (char*)lX4;

  for (int kt = 0; kt < 16; ++kt) {
    const int kb0 = kt * 64;
    __syncthreads();

    // ---- stage A tile (128 x 64) ----
    if constexpr (ABF16) {
#pragma unroll
      for (int i = 0; i < 4; ++i) {
        int q = i * 256 + tid;          // 1024 16B chunks
        int r = q >> 3, c = q & 7;
        const u32x4* src = (const u32x4*)(Abf + arow0 + (size_t)r * NN + kb0 + c * 8);
        *(u32x4*)(lAb + r * 128 + ((c ^ (r & 7)) << 4)) = *src;
      }
    } else {
#pragma unroll
      for (int i = 0; i < 8; ++i) {
        int q = i * 256 + tid;          // 2048 float4 chunks
        int r = q >> 4, c = q & 15;
        float4 v = *(const float4*)(Af32 + arow0 + (size_t)r * NN + kb0 + c * 4);
        s16x4 o;
        o.x = (short)f32_bf16(v.x);
        o.y = (short)f32_bf16(v.y);
        o.z = (short)f32_bf16(v.z);
        o.w = (short)f32_bf16(v.w);
        *(s16x4*)(lAb + r * 128 + ((c * 8) ^ ((r & 7) << 4))) = o;
      }
    }

    // ---- stage X tiles (3 x 16ch x 64k), from XT layout ----
    {
      int q = tid;
      int ct = q >> 7, rem = q & 127, ch = rem >> 3, c = rem & 7;
      const u32x4* src = (const u32x4*)(Xb + ct * SUBT + ch * NN + kb0 + c * 8);
      *(u32x4*)(lXb + ct * 2048 + ch * 128 + ((c ^ (ch & 7)) << 4)) = *src;
      if (tid < 128) {
        q = 256 + tid;
        ct = q >> 7; rem = q & 127; ch = rem >> 3; c = rem & 7;
        src = (const u32x4*)(Xb + ct * SUBT + ch * NN + kb0 + c * 8);
        *(u32x4*)(lXb + ct * 2048 + ch * 128 + ((c ^ (ch & 7)) << 4)) = *src;
      }
    }
    __syncthreads();

    // ---- MFMA ----
#pragma unroll
    for (int kb = 0; kb < 2; ++kb) {
      const int ko = kb * 64 + (l4 << 3);   // byte offset of k-fragment base
      bf16x8 afr[2];
#pragma unroll
      for (int mt = 0; mt < 2; ++mt) {
        int row = wave * 32 + mt * 16 + l15;
        int sw  = (row & 7) << 4;
        s16x8 t;
        t.lo = *(const s16x4*)(lAb + row * 128 + (ko ^ sw));
        t.hi = *(const s16x4*)(lAb + row * 128 + ((ko + 32) ^ sw));
        afr[mt] = __builtin_bit_cast(bf16x8, t);
      }
#pragma unroll
      for (int nt = 0; nt < 3; ++nt) {
        const int swx = (l15 & 7) << 4;
        const char* bp = lXb + nt * 2048 + l15 * 128;
        s16x8 t;
        t.lo = *(const s16x4*)(bp + (ko ^ swx));
        t.hi = *(const s16x4*)(bp + ((ko + 32) ^ swx));
        bf16x8 bfr = __builtin_bit_cast(bf16x8, t);
#pragma unroll
        for (int mt = 0; mt < 2; ++mt)
          acc[mt][nt] = __builtin_amdgcn_mfma_f32_16x16x32_bf16(afr[mt], bfr, acc[mt][nt], 0, 0, 0);
      }
    }
  }

  // ---- epilogue: write Y (bf16, XT layout). D: n=l&15 (col), m=(l>>4)*4+reg ----
#pragma unroll
  for (int mt = 0; mt < 2; ++mt)
#pragma unroll
    for (int nt = 0; nt < 3; ++nt) {
      int ch   = nt * 16 + l15;
      int row0 = mblk * 128 + wave * 32 + mt * 16 + (l4 << 2);
      s16x4 o;
      o.x = (short)f32_bf16(acc[mt][nt][0]);
      o.y = (short)f32_bf16(acc[mt][nt][1]);
      o.z = (short)f32_bf16(acc[mt][nt][2]);
      o.w = (short)f32_bf16(acc[mt][nt][3]);
      *(s16x4*)(Yb + (size_t)ch * NN + row0) = o;
    }
}

// ---------------------------------------------------------------------------
// gate_ru: r_u = sigmoid(h1 @ W_ru + b_ru); write H2 slot0 = [inputs, r*states],
// u to u_buf. One thread per (b, n) row.
// ---------------------------------------------------------------------------
__global__ __launch_bounds__(256)
void gate_ru(const unsigned short* __restrict__ H1,
             const float* __restrict__ W, const float* __restrict__ bias,
             const float* __restrict__ inputs, const float* __restrict__ states,
             unsigned short* __restrict__ H2, float* __restrict__ ubuf) {
  int gid = blockIdx.x * 256 + threadIdx.x;
  int b = gid >> 10, n = gid & 1023;
  const unsigned short* hb = H1 + (size_t)b * HB;
  float acc[64];
#pragma unroll
  for (int o = 0; o < 64; ++o) acc[o] = bias[o];
  for (int j = 0; j < 5; ++j) {
    const unsigned short* sb = hb + j * 3 * SUBT;
    for (int c = 0; c < 34; ++c) {
      float xv = bf16_f32(sb[(c >> 4) * SUBT + (c & 15) * NN + n]);
      const float* wr = W + (j * 34 + c) * 64;   // uniform address -> scalar loads
#pragma unroll
      for (int o = 0; o < 64; ++o) acc[o] = fmaf(xv, wr[o], acc[o]);
    }
  }
  unsigned short* xb = H2 + (size_t)b * HB;   // slot 0 of H2
  xb[0 * NN + n] = f32_bf16(inputs[gid * 2 + 0]);
  xb[1 * NN + n] = f32_bf16(inputs[gid * 2 + 1]);
#pragma unroll
  for (int o = 0; o < 32; ++o) {
    float r = 1.f / (1.f + __expf(-acc[o]));
    float u = 1.f / (1.f + __expf(-acc[32 + o]));
    float sv = states[gid * 32 + o];
    int ch = 2 + o;
    xb[(ch >> 4) * SUBT + (ch & 15) * NN + n] = f32_bf16(r * sv);
    ubuf[((size_t)b * 32 + o) * NN + n] = u;
  }
#pragma unroll
  for (int ch = 34; ch < 48; ++ch)
    xb[2 * SUBT + (ch & 15) * NN + n] = 0;
}

// ---------------------------------------------------------------------------
// gate_c: c = tanh(h2 @ W_c + b_c); out = u*states + (1-u)*c, written twice
// (reference returns (outputs, outputs)). Direct per-row vectorized stores.
// ---------------------------------------------------------------------------
__global__ __launch_bounds__(256)
void gate_c(const unsigned short* __restrict__ H2,
            const float* __restrict__ W, const float* __restrict__ bias,
            const float* __restrict__ states, const float* __restrict__ ubuf,
            float* __restrict__ out) {
  int gid = blockIdx.x * 256 + threadIdx.x;
  int b = gid >> 10, n = gid & 1023;
  const unsigned short* hb = H2 + (size_t)b * HB;
  float acc[32];
#pragma unroll
  for (int o = 0; o < 32; ++o) acc[o] = bias[o];
  for (int j = 0; j < 5; ++j) {
    const unsigned short* sb = hb + j * 3 * SUBT;
    for (int c = 0; c < 34; ++c) {
      float xv = bf16_f32(sb[(c >> 4) * SUBT + (c & 15) * NN + n]);
      const float* wr = W + (j * 34 + c) * 32;
#pragma unroll
      for (int o = 0; o < 32; ++o) acc[o] = fmaf(xv, wr[o], acc[o]);
    }
  }
  float res[32];
#pragma unroll
  for (int o = 0; o < 32; ++o) {
    float cc = tanhf(acc[o]);
    float u  = ubuf[((size_t)b * 32 + o) * NN + n];
    float sv = states[gid * 32 + o];
    res[o] = u * sv + (1.f - u) * cc;
  }
  float* o0 = out + (size_t)gid * 32;
#pragma unroll
  for (int q = 0; q < 8; ++q) {
    f32x4 v = { res[q * 4 + 0], res[q * 4 + 1], res[q * 4 + 2], res[q * 4 + 3] };
    *(f32x4*)(o0 + q * 4) = v;
    *(f32x4*)(o0 + OUTCOPY + q * 4) = v;   // second tuple copy
  }
}

// ---------------------------------------------------------------------------
extern "C" void kernel_launch(void* const* d_in, const int* in_sizes, int n_in,
                              void* d_out, int out_size, void* d_ws, size_t ws_size,
                              hipStream_t stream) {
  (void)in_sizes; (void)n_in; (void)out_size;
  const float* inputs   = (const float*)d_in[0];
  const float* supports = (const float*)d_in[1];
  const float* states   = (const float*)d_in[2];
  const float* W_ru     = (const float*)d_in[3];
  const float* b_ru     = (const float*)d_in[4];
  const float* W_c      = (const float*)d_in[5];
  const float* b_c      = (const float*)d_in[6];
  float* out = (float*)d_out;

  char* ws = (char*)d_ws;
  const size_t szA = 134217728;   // bf16 supports
  const size_t szH = 15728640;    // one H buffer
  const size_t szU = 4194304;     // u_buf
  const bool pathA = ws_size >= szA + 2 * szH + szU;
  const size_t off = pathA ? szA : 0;

  unsigned short* Abf = (unsigned short*)ws;
  unsigned short* H1  = (unsigned short*)(ws + off);
  unsigned short* H2  = (unsigned short*)(ws + off + szH);
  float*          ub  = (float*)(ws + off + 2 * szH);

  dim3 hgrid(8, 32, 2), blk(256);

  if (pathA)
    cvt_bf16<<<dim3(2048), blk, 0, stream>>>(supports, Abf, 16777216);

  pack_x1<<<dim3(128), blk, 0, stream>>>(inputs, states, H1);

  if (pathA) {
    hop_kernel<1><<<hgrid, blk, 0, stream>>>(nullptr, Abf, H1, H1, 0, 0, 1, 3);
    hop_kernel<1><<<hgrid, blk, 0, stream>>>(nullptr, Abf, H1, H1, 1, 3, 2, 4);
  } else {
    hop_kernel<0><<<hgrid, blk, 0, stream>>>(supports, nullptr, H1, H1, 0, 0, 1, 3);
    hop_kernel<0><<<hgrid, blk, 0, stream>>>(supports, nullptr, H1, H1, 1, 3, 2, 4);
  }

  gate_ru<<<dim3(128), blk, 0, stream>>>(H1, W_ru, b_ru, inputs, states, H2, ub);

  if (pathA) {
    hop_kernel<1><<<hgrid, blk, 0, stream>>>(nullptr, Abf, H2, H2, 0, 0, 1, 3);
    hop_kernel<1><<<hgrid, blk, 0, stream>>>(nullptr, Abf, H2, H2, 1, 3, 2, 4);
  } else {
    hop_kernel<0><<<hgrid, blk, 0, stream>>>(supports, nullptr, H2, H2, 0, 0, 1, 3);
    hop_kernel<0><<<hgrid, blk, 0, stream>>>(supports, nullptr, H2, H2, 1, 3, 2, 4);
  }

  gate_c<<<dim3(128), blk, 0, stream>>>(H2, W_c, b_c, states, ub, out);
}

// Round 3
// 320.616 us; speedup vs baseline: 1.0930x; 1.0930x over previous
//
#include <hip/hip_runtime.h>

// ---------------------------------------------------------------------------
// DCGRU cell on MI355X.
// B=32, N=1024, C_IN=2, H=32, S=2, K=2, NUM_MAT=5, c_cat=34, feats=5*34=170.
//
// Layouts:
//   supports (fp32 input): [B][S][N][N]
//   A_bf16 (ws):           [B][S][N][N] bf16
//   H buffers (ws):        per b: 5 slots x 3 ct x [16 ch][1024 n] bf16 ("XT")
//     slot j channel c of row n -> H[b*245760 + (3*j + c/16)*16384 + (c%16)*1024 + n]
//     channels 34..47 of each slot are zero padding.
//   u_buf (ws):            [B][32][N] fp32
//
// Output: d_out = (outputs, outputs), each B*N*H = 1,048,576 fp32.
// ---------------------------------------------------------------------------

#define NN   1024
#define HB   245760
#define SUBT 16384
#define OUTCOPY 1048576

typedef float  f32x4  __attribute__((ext_vector_type(4)));
typedef short  s16x4  __attribute__((ext_vector_type(4)));
typedef short  s16x8  __attribute__((ext_vector_type(8)));
typedef __bf16 bf16x8 __attribute__((ext_vector_type(8)));
typedef unsigned int u32x4 __attribute__((ext_vector_type(4)));

#define GAS __attribute__((address_space(1)))
#define LAS __attribute__((address_space(3)))

__device__ __forceinline__ unsigned short f32_bf16(float f) {
  unsigned int u = __float_as_uint(f);
  u += 0x7FFFu + ((u >> 16) & 1u);        // round-to-nearest-even
  return (unsigned short)(u >> 16);
}
__device__ __forceinline__ float bf16_f32(unsigned short h) {
  return __uint_as_float(((unsigned int)h) << 16);
}

// async 16B global -> LDS (linear dest: wave-uniform base + lane*16)
__device__ __forceinline__ void gload_lds16(const unsigned short* g, void* l) {
  __builtin_amdgcn_global_load_lds((const GAS void*)g, (LAS void*)l, 16, 0, 0);
}

// ---------------------------------------------------------------------------
// supports fp32 -> bf16
// ---------------------------------------------------------------------------
__global__ __launch_bounds__(256)
void cvt_bf16(const float* __restrict__ src, unsigned short* __restrict__ dst, int n4) {
  int i = blockIdx.x * 256 + threadIdx.x;
  int stride = gridDim.x * 256;
  for (; i < n4; i += stride) {
    float4 v = ((const float4*)src)[i];
    s16x4 o;
    o.x = (short)f32_bf16(v.x);
    o.y = (short)f32_bf16(v.y);
    o.z = (short)f32_bf16(v.z);
    o.w = (short)f32_bf16(v.w);
    ((s16x4*)dst)[i] = o;
  }
}

// ---------------------------------------------------------------------------
// pack x1 = [inputs, states] into H1 slot 0 (XT layout, bf16, zero pad)
// ---------------------------------------------------------------------------
__global__ __launch_bounds__(256)
void pack_x1(const float* __restrict__ inputs, const float* __restrict__ states,
             unsigned short* __restrict__ H1) {
  int gid = blockIdx.x * 256 + threadIdx.x;   // 0..32767
  int b = gid >> 10, n = gid & 1023;
  unsigned short* xb = H1 + (size_t)b * HB;   // slot 0
  xb[0 * NN + n] = f32_bf16(inputs[gid * 2 + 0]);
  xb[1 * NN + n] = f32_bf16(inputs[gid * 2 + 1]);
#pragma unroll
  for (int o = 0; o < 32; ++o) {
    int ch = 2 + o;
    xb[(ch >> 4) * SUBT + (ch & 15) * NN + n] = f32_bf16(states[gid * 32 + o]);
  }
#pragma unroll
  for (int ch = 34; ch < 48; ++ch)
    xb[2 * SUBT + (ch & 15) * NN + n] = 0;
}

// ---------------------------------------------------------------------------
// hop_fast: Y = A @ X per (b,s). BM=64 rows/block, BK=64, grid (16,32,2).
// Double-buffered LDS staged via global_load_lds (width 16) with pre-swizzled
// global source addresses; linear LDS dest; swizzled ds_read (XOR chunk^row&7).
// 2-phase pipeline: issue next tile's loads, compute current, barrier drains.
// LDS/buf: A 8192 B (64x64 bf16) + X 6144 B (3 x 16ch x 64k). 2 bufs = 28 KB.
// ---------------------------------------------------------------------------
__global__ __launch_bounds__(256, 4)
void hop_fast(const unsigned short* __restrict__ Abf,
              const unsigned short* __restrict__ Hin,
              unsigned short* __restrict__ Hout,
              int si0, int si1, int so0, int so1) {
  __shared__ u32x4 lds4[2][896];   // 2 x 14336 B, 16B-aligned

  const int tid  = threadIdx.x;
  const int wave = tid >> 6, lane = tid & 63;
  const int l15  = lane & 15,  l4  = lane >> 4;
  const int mblk = blockIdx.x, b = blockIdx.y, s = blockIdx.z;
  const int slot_in  = s ? si1 : si0;
  const int slot_out = s ? so1 : so0;

  const unsigned short* Xb = Hin  + (size_t)b * HB + (size_t)slot_in  * 3 * SUBT;
  unsigned short*       Yb = Hout + (size_t)b * HB + (size_t)slot_out * 3 * SUBT;
  const size_t arow0 = ((size_t)(b * 2 + s) * NN + (size_t)mblk * 64) * NN;

  f32x4 acc[3];
#pragma unroll
  for (int nt = 0; nt < 3; ++nt)
#pragma unroll
    for (int e = 0; e < 4; ++e) acc[nt][e] = 0.f;

  // stage one K-tile (A 512 chunks + X 384 chunks of 16B) into buffer bufi
  auto STAGE = [&](int bufi, int kb0) {
    char* base = (char*)&lds4[bufi][0];
    // A: chunk q -> row r=q>>3, swizzled slot cs=q&7 holds source col (cs^(r&7))
#pragma unroll
    for (int i = 0; i < 2; ++i) {
      int q = i * 256 + tid;
      int r = q >> 3, cs = q & 7;
      const unsigned short* g = Abf + arow0 + (size_t)r * NN + kb0 + ((cs ^ (r & 7)) << 3);
      gload_lds16(g, base + (i * 256 + wave * 64) * 16);
    }
    // X: chunk q -> ct=q>>7, ch=(q&127)>>3, cs=q&7
    {
      int q = tid;
      int ct = q >> 7, rem = q & 127, ch = rem >> 3, cs = rem & 7;
      const unsigned short* g = Xb + ct * SUBT + ch * NN + kb0 + ((cs ^ (ch & 7)) << 3);
      gload_lds16(g, base + 8192 + (wave * 64) * 16);
      if (wave < 2) {
        q = 256 + tid;
        ct = q >> 7; rem = q & 127; ch = rem >> 3; cs = rem & 7;
        g = Xb + ct * SUBT + ch * NN + kb0 + ((cs ^ (ch & 7)) << 3);
        gload_lds16(g, base + 8192 + (256 + wave * 64) * 16);
      }
    }
  };

  STAGE(0, 0);
  __syncthreads();          // vmcnt(0) drain: buffer 0 ready

  const int row = wave * 16 + l15;       // A row within 64-row tile
  const int sw  = (row & 7) << 4;
  const int swx = (l15 & 7) << 4;

  int cur = 0;
  for (int kt = 0; kt < 16; ++kt) {
    if (kt < 15) STAGE(cur ^ 1, (kt + 1) << 6);   // prefetch next tile

    const char* lAb = (const char*)&lds4[cur][0];
    const char* lXb = lAb + 8192;

    __builtin_amdgcn_s_setprio(1);
#pragma unroll
    for (int kb = 0; kb < 2; ++kb) {
      const int ko = kb * 64 + (l4 << 3);
      s16x8 ta;
      ta.lo = *(const s16x4*)(lAb + row * 128 + (ko ^ sw));
      ta.hi = *(const s16x4*)(lAb + row * 128 + ((ko + 32) ^ sw));
      bf16x8 afr = __builtin_bit_cast(bf16x8, ta);
#pragma unroll
      for (int nt = 0; nt < 3; ++nt) {
        const char* bp = lXb + nt * 2048 + l15 * 128;
        s16x8 tb;
        tb.lo = *(const s16x4*)(bp + (ko ^ swx));
        tb.hi = *(const s16x4*)(bp + ((ko + 32) ^ swx));
        bf16x8 bfr = __builtin_bit_cast(bf16x8, tb);
        acc[nt] = __builtin_amdgcn_mfma_f32_16x16x32_bf16(afr, bfr, acc[nt], 0, 0, 0);
      }
    }
    __builtin_amdgcn_s_setprio(0);

    if (kt < 15) __syncthreads();   // drains vmcnt(0): next buffer ready
    cur ^= 1;
  }

  // epilogue: D layout col(n)=l15, row(m)=l4*4+reg
  const int row0 = mblk * 64 + wave * 16 + (l4 << 2);
#pragma unroll
  for (int nt = 0; nt < 3; ++nt) {
    int ch = nt * 16 + l15;
    s16x4 o;
    o.x = (short)f32_bf16(acc[nt][0]);
    o.y = (short)f32_bf16(acc[nt][1]);
    o.z = (short)f32_bf16(acc[nt][2]);
    o.w = (short)f32_bf16(acc[nt][3]);
    *(s16x4*)(Yb + (size_t)ch * NN + row0) = o;
  }
}

// ---------------------------------------------------------------------------
// hop_slow: fallback when ws can't hold A_bf16 — reg-staged fp32 A, BM=128.
// ---------------------------------------------------------------------------
__global__ __launch_bounds__(256)
void hop_slow(const float* __restrict__ Af32,
              const unsigned short* __restrict__ Hin,
              unsigned short* __restrict__ Hout,
              int si0, int si1, int so0, int so1) {
  __shared__ u32x4 lA4[1024];   // 16 KB
  __shared__ u32x4 lX4[384];    // 6 KB

  const int tid  = threadIdx.x;
  const int wave = tid >> 6, lane = tid & 63;
  const int l15  = lane & 15,  l4  = lane >> 4;
  const int mblk = blockIdx.x, b = blockIdx.y, s = blockIdx.z;
  const int slot_in  = s ? si1 : si0;
  const int slot_out = s ? so1 : so0;

  const unsigned short* Xb = Hin  + (size_t)b * HB + (size_t)slot_in  * 3 * SUBT;
  unsigned short*       Yb = Hout + (size_t)b * HB + (size_t)slot_out * 3 * SUBT;
  const size_t arow0 = ((size_t)(b * 2 + s) * NN + (size_t)mblk * 128) * NN;

  f32x4 acc[2][3];
#pragma unroll
  for (int mt = 0; mt < 2; ++mt)
#pragma unroll
    for (int nt = 0; nt < 3; ++nt)
#pragma unroll
      for (int e = 0; e < 4; ++e) acc[mt][nt][e] = 0.f;

  char* lAb = (char*)lA4;
  char* lXb = (char*)lX4;

  for (int kt = 0; kt < 16; ++kt) {
    const int kb0 = kt * 64;
    __syncthreads();
#pragma unroll
    for (int i = 0; i < 8; ++i) {
      int q = i * 256 + tid;
      int r = q >> 4, c = q & 15;
      float4 v = *(const float4*)(Af32 + arow0 + (size_t)r * NN + kb0 + c * 4);
      s16x4 o;
      o.x = (short)f32_bf16(v.x);
      o.y = (short)f32_bf16(v.y);
      o.z = (short)f32_bf16(v.z);
      o.w = (short)f32_bf16(v.w);
      *(s16x4*)(lAb + r * 128 + ((c * 8) ^ ((r & 7) << 4))) = o;
    }
    {
      int q = tid;
      int ct = q >> 7, rem = q & 127, ch = rem >> 3, c = rem & 7;
      const u32x4* src = (const u32x4*)(Xb + ct * SUBT + ch * NN + kb0 + c * 8);
      *(u32x4*)(lXb + ct * 2048 + ch * 128 + ((c ^ (ch & 7)) << 4)) = *src;
      if (tid < 128) {
        q = 256 + tid;
        ct = q >> 7; rem = q & 127; ch = rem >> 3; c = rem & 7;
        src = (const u32x4*)(Xb + ct * SUBT + ch * NN + kb0 + c * 8);
        *(u32x4*)(lXb + ct * 2048 + ch * 128 + ((c ^ (ch & 7)) << 4)) = *src;
      }
    }
    __syncthreads();
#pragma unroll
    for (int kb = 0; kb < 2; ++kb) {
      const int ko = kb * 64 + (l4 << 3);
      bf16x8 afr[2];
#pragma unroll
      for (int mt = 0; mt < 2; ++mt) {
        int row = wave * 32 + mt * 16 + l15;
        int sw  = (row & 7) << 4;
        s16x8 t;
        t.lo = *(const s16x4*)(lAb + row * 128 + (ko ^ sw));
        t.hi = *(const s16x4*)(lAb + row * 128 + ((ko + 32) ^ sw));
        afr[mt] = __builtin_bit_cast(bf16x8, t);
      }
#pragma unroll
      for (int nt = 0; nt < 3; ++nt) {
        const int swx = (l15 & 7) << 4;
        const char* bp = lXb + nt * 2048 + l15 * 128;
        s16x8 t;
        t.lo = *(const s16x4*)(bp + (ko ^ swx));
        t.hi = *(const s16x4*)(bp + ((ko + 32) ^ swx));
        bf16x8 bfr = __builtin_bit_cast(bf16x8, t);
#pragma unroll
        for (int mt = 0; mt < 2; ++mt)
          acc[mt][nt] = __builtin_amdgcn_mfma_f32_16x16x32_bf16(afr[mt], bfr, acc[mt][nt], 0, 0, 0);
      }
    }
  }

#pragma unroll
  for (int mt = 0; mt < 2; ++mt)
#pragma unroll
    for (int nt = 0; nt < 3; ++nt) {
      int ch   = nt * 16 + l15;
      int row0 = mblk * 128 + wave * 32 + mt * 16 + (l4 << 2);
      s16x4 o;
      o.x = (short)f32_bf16(acc[mt][nt][0]);
      o.y = (short)f32_bf16(acc[mt][nt][1]);
      o.z = (short)f32_bf16(acc[mt][nt][2]);
      o.w = (short)f32_bf16(acc[mt][nt][3]);
      *(s16x4*)(Yb + (size_t)ch * NN + row0) = o;
    }
}

// ---------------------------------------------------------------------------
// gate_ru: r_u = sigmoid(h1 @ W_ru + b_ru); H2 slot0 = [inputs, r*states]; u out.
// ---------------------------------------------------------------------------
__global__ __launch_bounds__(256)
void gate_ru(const unsigned short* __restrict__ H1,
             const float* __restrict__ W, const float* __restrict__ bias,
             const float* __restrict__ inputs, const float* __restrict__ states,
             unsigned short* __restrict__ H2, float* __restrict__ ubuf) {
  int gid = blockIdx.x * 256 + threadIdx.x;
  int b = gid >> 10, n = gid & 1023;
  const unsigned short* hb = H1 + (size_t)b * HB;
  float acc[64];
#pragma unroll
  for (int o = 0; o < 64; ++o) acc[o] = bias[o];
  for (int j = 0; j < 5; ++j) {
    const unsigned short* sb = hb + j * 3 * SUBT;
    for (int c = 0; c < 34; ++c) {
      float xv = bf16_f32(sb[(c >> 4) * SUBT + (c & 15) * NN + n]);
      const float* wr = W + (j * 34 + c) * 64;
#pragma unroll
      for (int o = 0; o < 64; ++o) acc[o] = fmaf(xv, wr[o], acc[o]);
    }
  }
  unsigned short* xb = H2 + (size_t)b * HB;
  xb[0 * NN + n] = f32_bf16(inputs[gid * 2 + 0]);
  xb[1 * NN + n] = f32_bf16(inputs[gid * 2 + 1]);
#pragma unroll
  for (int o = 0; o < 32; ++o) {
    float r = 1.f / (1.f + __expf(-acc[o]));
    float u = 1.f / (1.f + __expf(-acc[32 + o]));
    float sv = states[gid * 32 + o];
    int ch = 2 + o;
    xb[(ch >> 4) * SUBT + (ch & 15) * NN + n] = f32_bf16(r * sv);
    ubuf[((size_t)b * 32 + o) * NN + n] = u;
  }
#pragma unroll
  for (int ch = 34; ch < 48; ++ch)
    xb[2 * SUBT + (ch & 15) * NN + n] = 0;
}

// ---------------------------------------------------------------------------
// gate_c: c = tanh(h2 @ W_c + b_c); out = u*states + (1-u)*c (written twice)
// ---------------------------------------------------------------------------
__global__ __launch_bounds__(256)
void gate_c(const unsigned short* __restrict__ H2,
            const float* __restrict__ W, const float* __restrict__ bias,
            const float* __restrict__ states, const float* __restrict__ ubuf,
            float* __restrict__ out) {
  int gid = blockIdx.x * 256 + threadIdx.x;
  int b = gid >> 10, n = gid & 1023;
  const unsigned short* hb = H2 + (size_t)b * HB;
  float acc[32];
#pragma unroll
  for (int o = 0; o < 32; ++o) acc[o] = bias[o];
  for (int j = 0; j < 5; ++j) {
    const unsigned short* sb = hb + j * 3 * SUBT;
    for (int c = 0; c < 34; ++c) {
      float xv = bf16_f32(sb[(c >> 4) * SUBT + (c & 15) * NN + n]);
      const float* wr = W + (j * 34 + c) * 32;
#pragma unroll
      for (int o = 0; o < 32; ++o) acc[o] = fmaf(xv, wr[o], acc[o]);
    }
  }
  float res[32];
#pragma unroll
  for (int o = 0; o < 32; ++o) {
    float cc = tanhf(acc[o]);
    float u  = ubuf[((size_t)b * 32 + o) * NN + n];
    float sv = states[gid * 32 + o];
    res[o] = u * sv + (1.f - u) * cc;
  }
  float* o0 = out + (size_t)gid * 32;
#pragma unroll
  for (int q = 0; q < 8; ++q) {
    f32x4 v = { res[q * 4 + 0], res[q * 4 + 1], res[q * 4 + 2], res[q * 4 + 3] };
    *(f32x4*)(o0 + q * 4) = v;
    *(f32x4*)(o0 + OUTCOPY + q * 4) = v;
  }
}

// ---------------------------------------------------------------------------
extern "C" void kernel_launch(void* const* d_in, const int* in_sizes, int n_in,
                              void* d_out, int out_size, void* d_ws, size_t ws_size,
                              hipStream_t stream) {
  (void)in_sizes; (void)n_in; (void)out_size;
  const float* inputs   = (const float*)d_in[0];
  const float* supports = (const float*)d_in[1];
  const float* states   = (const float*)d_in[2];
  const float* W_ru     = (const float*)d_in[3];
  const float* b_ru     = (const float*)d_in[4];
  const float* W_c      = (const float*)d_in[5];
  const float* b_c      = (const float*)d_in[6];
  float* out = (float*)d_out;

  char* ws = (char*)d_ws;
  const size_t szA = 134217728;   // bf16 supports
  const size_t szH = 15728640;    // one H buffer
  const size_t szU = 4194304;     // u_buf
  const bool pathA = ws_size >= szA + 2 * szH + szU;
  const size_t off = pathA ? szA : 0;

  unsigned short* Abf = (unsigned short*)ws;
  unsigned short* H1  = (unsigned short*)(ws + off);
  unsigned short* H2  = (unsigned short*)(ws + off + szH);
  float*          ub  = (float*)(ws + off + 2 * szH);

  dim3 fgrid(16, 32, 2), sgrid(8, 32, 2), blk(256);

  if (pathA)
    cvt_bf16<<<dim3(2048), blk, 0, stream>>>(supports, Abf, 16777216);

  pack_x1<<<dim3(128), blk, 0, stream>>>(inputs, states, H1);

  if (pathA) {
    hop_fast<<<fgrid, blk, 0, stream>>>(Abf, H1, H1, 0, 0, 1, 3);
    hop_fast<<<fgrid, blk, 0, stream>>>(Abf, H1, H1, 1, 3, 2, 4);
  } else {
    hop_slow<<<sgrid, blk, 0, stream>>>(supports, H1, H1, 0, 0, 1, 3);
    hop_slow<<<sgrid, blk, 0, stream>>>(supports, H1, H1, 1, 3, 2, 4);
  }

  gate_ru<<<dim3(128), blk, 0, stream>>>(H1, W_ru, b_ru, inputs, states, H2, ub);

  if (pathA) {
    hop_fast<<<fgrid, blk, 0, stream>>>(Abf, H2, H2, 0, 0, 1, 3);
    hop_fast<<<fgrid, blk, 0, stream>>>(Abf, H2, H2, 1, 3, 2, 4);
  } else {
    hop_slow<<<sgrid, blk, 0, stream>>>(supports, H2, H2, 0, 0, 1, 3);
    hop_slow<<<sgrid, blk, 0, stream>>>(supports, H2, H2, 1, 3, 2, 4);
  }

  gate_c<<<dim3(128), blk, 0, stream>>>(H2, W_c, b_c, states, ub, out);
}